// Round 12
// baseline (41.280 us; speedup 1.0000x reference)
//
#include <hip/hip_runtime.h>

#define IMG   512
#define HW    (IMG * IMG)
#define NCH   24     // 8 batches * 3 channels
#define LDSW  68     // 64 + 2*2 halo
#define LDSN  (LDSW * LDSW)   // 4624 floats = 18496 B

__device__ __forceinline__ float fexp2(float x) {
#if __has_builtin(__builtin_amdgcn_exp2f)
    return __builtin_amdgcn_exp2f(x);
#else
    float r; asm("v_exp_f32 %0, %1" : "=v"(r) : "v"(x)); return r;
#endif
}
__device__ __forceinline__ float frcp(float x) {
#if __has_builtin(__builtin_amdgcn_rcpf)
    return __builtin_amdgcn_rcpf(x);
#else
    float r; asm("v_rcp_f32 %0, %1" : "=v"(r) : "v"(x)); return r;
#endif
}

// exp(-r2/2) (double, folded at compile time)
__device__ __forceinline__ constexpr double exs(int r2) {
    return (r2 == 0) ? 1.0
         : (r2 == 1) ? 0.60653065971263342
         : (r2 == 2) ? 0.36787944117144233
         : (r2 == 4) ? 0.13533528323661270
         : (r2 == 5) ? 0.08208499862389880
         : (r2 == 8) ? 0.01831563888873418 : 0.0;
}
#define SSUM 6.16892408102888092
__device__ __forceinline__ constexpr float k1(int d)  { return (float)exs(d * d); }
__device__ __forceinline__ constexpr float k1n(int d) { return (float)(exs(d * d) / SSUM); }
// -50/ln2 (intensity) and -0.5/ln2 (spatial, per unit r2), log2 domain
#define NEG50  -72.134752044448169f
#define LG     -0.72134752044448169f

// Grid: 24 channels * 64 blocks (8x8 of 64x64-px regions); 256 thr = 16x16 tiles of 4x4 px
__global__ __launch_bounds__(256) void aa_kernel(const float* __restrict__ in,
                                                 float* __restrict__ out) {
    __shared__ float sm[LDSN];

    const int bid = blockIdx.x;
    const int ch  = bid >> 6;
    const int b2  = bid & 63;
    const int by  = b2 >> 3, bx = b2 & 7;
    const int y0b = by * 64, x0b = bx * 64;
    const float* __restrict__ img = in + ch * HW;
    const int tid = threadIdx.x;

    // ---- cooperative stage: 68x68 window, reflect applied once per element ----
    for (int idx = tid; idx < LDSN; idx += 256) {
        const int lr = idx / LDSW;            // constant divisor -> magic mul
        const int lc = idx - lr * LDSW;
        int gr = y0b + lr - 2;
        int gc = x0b + lc - 2;
        gr = (gr < 0) ? -gr : ((gr >= IMG) ? 2 * IMG - 2 - gr : gr);
        gc = (gc < 0) ? -gc : ((gc >= IMG) ? 2 * IMG - 2 - gc : gc);
        sm[idx] = img[gr * IMG + gc];
    }
    __syncthreads();

    const int tr = tid >> 4, tc = tid & 15;
    const int py = y0b + tr * 4;              // tile origin pixel (row)
    const int px = x0b + tc * 4;              // tile origin pixel (col)

    // ---- 8x8 window from LDS: 16 aligned b128 reads ----
    float v[8][8];
    #pragma unroll
    for (int r = 0; r < 8; ++r) {
        const float4* p0 = (const float4*)&sm[(tr * 4 + r) * LDSW + tc * 4];
        const float4 a = p0[0], b = p0[1];
        v[r][0] = a.x; v[r][1] = a.y; v[r][2] = a.z; v[r][3] = a.w;
        v[r][4] = b.x; v[r][5] = b.y; v[r][6] = b.z; v[r][7] = b.w;
    }

    // ---- bilateral: 4x4 tile, symmetric weight sharing (R9 body) ----
    float ws[16], bs[16];
    #pragma unroll
    for (int p = 0; p < 16; ++p) {
        const int pr = p >> 2, pc = p & 3;
        ws[p] = 1.0f;                          // center tap folded in (w == 1)
        bs[p] = v[pr + 2][pc + 2];
    }

    constexpr int PDI[12] = {0, 0, 1,  1, 1, 1, 1, 2,  2, 2, 2, 2};
    constexpr int PDJ[12] = {1, 2, -2, -1, 0, 1, 2, -2, -1, 0, 1, 2};

    // positive pass: each shared weight once; scatter to both endpoints
    #pragma unroll
    for (int o = 0; o < 12; ++o) {
        const int di = PDI[o], dj = PDJ[o];
        const int r2 = di * di + dj * dj;
        const float lsw = LG * (float)r2;
        float wt[16];
        #pragma unroll
        for (int p = 0; p < 16; ++p) {
            const int pr = p >> 2, pc = p & 3;
            const float d = v[pr + 2 + di][pc + 2 + dj] - v[pr + 2][pc + 2];
            wt[p] = fexp2(fmaf(d * d, NEG50, lsw));
        }
        #pragma unroll
        for (int p = 0; p < 16; ++p) {
            const int pr = p >> 2, pc = p & 3;
            const float vp = v[pr + 2][pc + 2];
            const float vt = v[pr + 2 + di][pc + 2 + dj];
            ws[p] += wt[p];
            bs[p] = fmaf(wt[p], vt, bs[p]);
            const int qr = pr + di, qc = pc + dj;
            if (qr >= 0 && qr < 4 && qc >= 0 && qc < 4) {   // compile-time
                const int q = qr * 4 + qc;
                ws[q] += wt[p];
                bs[q] = fmaf(wt[p], vp, bs[q]);
            }
        }
    }
    // negative pass: only instances whose mirror endpoint is outside the tile
    #pragma unroll
    for (int o = 0; o < 12; ++o) {
        const int di = -PDI[o], dj = -PDJ[o];
        const int r2 = di * di + dj * dj;
        const float lsw = LG * (float)r2;
        float wt[16];
        #pragma unroll
        for (int p = 0; p < 16; ++p) {
            const int pr = p >> 2, pc = p & 3;
            const int qr = pr + di, qc = pc + dj;
            if (qr < 0 || qr >= 4 || qc < 0 || qc >= 4) {   // compile-time
                const float d = v[pr + 2 + di][pc + 2 + dj] - v[pr + 2][pc + 2];
                wt[p] = fexp2(fmaf(d * d, NEG50, lsw));
            }
        }
        #pragma unroll
        for (int p = 0; p < 16; ++p) {
            const int pr = p >> 2, pc = p & 3;
            const int qr = pr + di, qc = pc + dj;
            if (qr < 0 || qr >= 4 || qc < 0 || qc >= 4) {
                const float vt = v[pr + 2 + di][pc + 2 + dj];
                ws[p] += wt[p];
                bs[p] = fmaf(wt[p], vt, bs[p]);
            }
        }
    }

    // ---- gaussian: separable, zero-pad masks (all-1 for interior blocks) ----
    float xin[8];
    #pragma unroll
    for (int c = 0; c < 8; ++c) {
        const int gx = px + c - 2;
        xin[c] = ((gx >= 0) & (gx < IMG)) ? 1.0f : 0.0f;
    }

    float* op = out + ch * HW + py * IMG + px;
    #pragma unroll
    for (int yr = 0; yr < 4; ++yr) {
        float kr[5];
        #pragma unroll
        for (int i = 0; i < 5; ++i) {
            const int gy = py + yr + i - 2;
            kr[i] = ((gy >= 0) & (gy < IMG)) ? k1(i - 2) : 0.0f;
        }
        float csm[8];
        #pragma unroll
        for (int c = 0; c < 8; ++c) {
            float s = kr[0] * v[yr][c];
            s = fmaf(kr[1], v[yr + 1][c], s);
            s = fmaf(kr[2], v[yr + 2][c], s);
            s = fmaf(kr[3], v[yr + 3][c], s);
            s = fmaf(kr[4], v[yr + 4][c], s);
            csm[c] = s * xin[c];
        }
        float res[4];
        #pragma unroll
        for (int pc = 0; pc < 4; ++pc) {
            float g = k1n(2) * csm[pc];
            g = fmaf(k1n(1), csm[pc + 1], g);
            g = fmaf(k1n(0), csm[pc + 2], g);
            g = fmaf(k1n(1), csm[pc + 3], g);
            g = fmaf(k1n(2), csm[pc + 4], g);
            const int p = yr * 4 + pc;
            res[pc] = fmaf(0.6f, g, 0.4f * (bs[p] * frcp(ws[p] + 1e-8f)));
        }
        *(float4*)(op + yr * IMG) = make_float4(res[0], res[1], res[2], res[3]);
    }
}

extern "C" void kernel_launch(void* const* d_in, const int* in_sizes, int n_in,
                              void* d_out, int out_size, void* d_ws, size_t ws_size,
                              hipStream_t stream) {
    const float* img = (const float*)d_in[0];
    float* out = (float*)d_out;
    aa_kernel<<<NCH * 64, 256, 0, stream>>>(img, out);
}